// Round 8
// baseline (118.218 us; speedup 1.0000x reference)
//
#include <hip/hip_runtime.h>

typedef short bf16x8 __attribute__((ext_vector_type(8)));
typedef short bf16x4 __attribute__((ext_vector_type(4)));
typedef float f32x4 __attribute__((ext_vector_type(4)));
typedef int i32x4 __attribute__((ext_vector_type(4)));
typedef int i32x2 __attribute__((ext_vector_type(2)));

#define MFMA16x16x32(a, b, c) __builtin_amdgcn_mfma_f32_16x16x32_bf16(a, b, c, 0, 0, 0)
#define TRR(dst, a) asm volatile("ds_read_b64_tr_b16 %0, %1" : "=v"(dst) : "v"(a))

__device__ __forceinline__ unsigned short f2bf(float f) {
  union { float f; unsigned u; } v; v.f = f;
  unsigned u = v.u + 0x7FFFu + ((v.u >> 16) & 1u);
  return (unsigned short)(u >> 16);
}

__device__ __forceinline__ unsigned cvtpk(float lo, float hi) {
  unsigned r;
  asm("v_cvt_pk_bf16_f32 %0, %1, %2" : "=v"(r) : "v"(lo), "v"(hi));
  return r;
}

__device__ __forceinline__ float max3f(float a, float b, float c) {
  float d;
  asm("v_max3_f32 %0, %1, %2, %3" : "=v"(d) : "v"(a), "v"(b), "v"(c));
  return d;
}

__device__ __forceinline__ void gload16(const void* g, void* l) {
  __builtin_amdgcn_global_load_lds((const __attribute__((address_space(1))) void*)g,
                                   (__attribute__((address_space(3))) void*)l, 16, 0, 0);
}

__device__ __forceinline__ unsigned ldsoff(const void* p) {
  return (unsigned)(unsigned long long)(const __attribute__((address_space(3))) void*)p;
}

// ---------------- fp32 -> bf16 elementwise (x) ----------------
__global__ __launch_bounds__(256) void conv_bf16(const float* __restrict__ in,
                                                 unsigned short* __restrict__ out, int n8) {
  int i = blockIdx.x * 256 + threadIdx.x;
  if (i >= n8) return;
  const float4* p = reinterpret_cast<const float4*>(in + (long)i * 8);
  float4 a = p[0], b = p[1];
  i32x4 o;
  o[0] = cvtpk(a.x, a.y); o[1] = cvtpk(a.z, a.w);
  o[2] = cvtpk(b.x, b.y); o[3] = cvtpk(b.z, b.w);
  *reinterpret_cast<i32x4*>(out + (long)i * 8) = o;
}

// ---------------- transpose + convert: W[K][N] f32 -> Wt[N][K] bf16 ----------------
__global__ __launch_bounds__(256) void trans_f32_bf16(const float* __restrict__ W,
                                                      unsigned short* __restrict__ Wt,
                                                      int K, int N) {
  __shared__ float tile[32][33];
  int n0 = blockIdx.x << 5, k0 = blockIdx.y << 5;
  int tx = threadIdx.x, ty = threadIdx.y;  // 32 x 8
#pragma unroll
  for (int i = 0; i < 32; i += 8)
    tile[ty + i][tx] = W[(long)(k0 + ty + i) * N + n0 + tx];
  __syncthreads();
#pragma unroll
  for (int i = 0; i < 32; i += 8)
    Wt[(long)(n0 + ty + i) * K + k0 + tx] = f2bf(tile[tx][ty + i]);
}

// ---------------- GEMM: C[M,N] = A[M,K] @ Bt[N,K]^T + bias, bf16 inputs ----------------
template <int BF16OUT>
__global__ __launch_bounds__(256) void gemm_bt(const unsigned short* __restrict__ A,
                                               const unsigned short* __restrict__ Bt,
                                               const float* __restrict__ bias,
                                               void* __restrict__ Cv,
                                               int M, int N, int K) {
  __shared__ __align__(128) unsigned short As[4096];  // [128][32]
  __shared__ __align__(128) unsigned short Bs[4096];  // [128][32]
  int t = threadIdx.x;
  int w = t >> 6, l = t & 63;
  int g = l >> 4, m16 = l & 15;
  int wr = w >> 1, wc = w & 1;
  long am0 = (long)blockIdx.y << 7;
  long bn0 = (long)blockIdx.x << 7;
  f32x4 acc[4][4];
#pragma unroll
  for (int i = 0; i < 4; ++i)
#pragma unroll
    for (int j = 0; j < 4; ++j) acc[i][j] = (f32x4){0.f, 0.f, 0.f, 0.f};

  for (int k0 = 0; k0 < K; k0 += 32) {
#pragma unroll
    for (int i = 0; i < 2; ++i) {
      int seg = i * 4 + w;
      int flat = (seg << 9) + (l << 3);
      int r_ = flat >> 5, c_ = flat & 31;
      gload16(A + (am0 + r_) * K + k0 + c_, &As[seg << 9]);
      gload16(Bt + (bn0 + r_) * K + k0 + c_, &Bs[seg << 9]);
    }
    __syncthreads();
    bf16x8 af[4], bfr[4];
#pragma unroll
    for (int im = 0; im < 4; ++im)
      af[im] = *(const bf16x8*)&As[((wr << 6) + (im << 4) + m16) * 32 + (g << 3)];
#pragma unroll
    for (int in = 0; in < 4; ++in)
      bfr[in] = *(const bf16x8*)&Bs[((wc << 6) + (in << 4) + m16) * 32 + (g << 3)];
    __builtin_amdgcn_s_setprio(1);
#pragma unroll
    for (int im = 0; im < 4; ++im)
#pragma unroll
      for (int in = 0; in < 4; ++in)
        acc[im][in] = MFMA16x16x32(af[im], bfr[in], acc[im][in]);
    __builtin_amdgcn_s_setprio(0);
    __syncthreads();
  }

#pragma unroll
  for (int im = 0; im < 4; ++im) {
#pragma unroll
    for (int in = 0; in < 4; ++in) {
      long col = bn0 + (wc << 6) + (in << 4) + m16;
      float bval = bias[col];
#pragma unroll
      for (int r = 0; r < 4; ++r) {
        long row = am0 + (wr << 6) + (im << 4) + (g << 2) + r;
        float v = acc[im][in][r] + bval;
        if (BF16OUT)
          ((unsigned short*)Cv)[row * N + col] = f2bf(v);
        else
          ((float*)Cv)[row * N + col] = v;
      }
    }
  }
}

// ---------------- causal flash attention (dual q-tile, KVBLK=128 supersteps) ---------
// grid: (B*H=32, 16), block 256 (4 waves). Block y processes q-tiles A=y and B=31-y
// CONCURRENTLY over a shared key loop of nt = (31-y)/2+1 supersteps (128 keys each).
// K-fragments and V tr-reads are loaded once per superstep and feed BOTH tiles'
// QK^T / PV (halves LDS-read+staging per MFMA; two independent chains give ILP).
// lsum kept as per-lane f32x4 partial, rescaled like O, reduced once in epilogue
// (removes 2 shfl chains per superstep).
__global__ __launch_bounds__(256, 2) void attn_fwd(const unsigned short* __restrict__ qkv,
                                                   unsigned short* __restrict__ out) {
  const int D3 = 3072;
  const float C1 = 0.18033688f;    // 0.125 * log2(e)
  const float THR = 11.5415603f;   // 8 * log2(e)
  __shared__ __align__(128) unsigned short Ks[2][8192];
  __shared__ __align__(128) unsigned short Vs[2][8192];
  int b = blockIdx.x >> 4, h = blockIdx.x & 15;
  int y = blockIdx.y;
  int t = threadIdx.x;
  int w = t >> 6, l = t & 63;
  int g = l >> 4, m16 = l & 15;
  long base = (long)b * 2048 * D3;
  const unsigned short* kbase = qkv + base + 1024 + h * 64;
  const unsigned short* vbase = qkv + base + 2048 + h * 64;

  int l8 = l >> 3, sc = l & 7;
  int kof = (w * 8 + l8) * D3 + ((sc ^ l8) << 3);
  int vof = ((w * 8 + l8) * 4 + (sc >> 1)) * D3 + ((sc & 1) << 3);
  const f32x4 zero4 = (f32x4){0.f, 0.f, 0.f, 0.f};

  int qtA = y, qtB = 31 - y;
  int ssA = (qtA >> 1) + 1;        // supersteps tile A needs
  int nt = (qtB >> 1) + 1;         // shared loop length (>= ssA)
  int qrowA = (qtA << 6) + (w << 4) + m16;
  int qrowB = (qtB << 6) + (w << 4) + m16;

  const unsigned short* qpA = qkv + base + (long)qrowA * D3 + h * 64;
  const unsigned short* qpB = qkv + base + (long)qrowB * D3 + h * 64;
  bf16x8 qfA0 = *(const bf16x8*)(qpA + g * 8);
  bf16x8 qfA1 = *(const bf16x8*)(qpA + 32 + g * 8);
  bf16x8 qfB0 = *(const bf16x8*)(qpB + g * 8);
  bf16x8 qfB1 = *(const bf16x8*)(qpB + 32 + g * 8);

  f32x4 OA[4], OB[4];
#pragma unroll
  for (int d = 0; d < 4; ++d) { OA[d] = zero4; OB[d] = zero4; }
  f32x4 lsvA = zero4, lsvB = zero4;
  float m2A = -1e30f, m2B = -1e30f;

#pragma unroll
  for (int i = 0; i < 4; ++i) {
    gload16(kbase + kof + i * 32 * D3, &Ks[0][(i << 11) + (w << 9)]);
    gload16(vbase + vof + (i << 4), &Vs[0][(i << 11) + (w << 9)]);
  }
  __syncthreads();

  int buf = 0;
  for (int ss = 0; ss < nt; ++ss) {
    if (ss + 1 < nt) {
      long off = (long)(ss + 1) * 128 * D3;
#pragma unroll
      for (int i = 0; i < 4; ++i) {
        gload16(kbase + off + kof + i * 32 * D3, &Ks[buf ^ 1][(i << 11) + (w << 9)]);
        gload16(vbase + off + vof + (i << 4), &Vs[buf ^ 1][(i << 11) + (w << 9)]);
      }
    }
    // V transpose-reads (shared by both tiles), issued early.
    unsigned va = ldsoff(&Vs[buf][0]) + (g << 7) + (m16 << 3);
    bf16x4 tLo[4][4], tHi[4][4];  // [G 32-key group][d block]
#pragma unroll
    for (int G = 0; G < 4; ++G)
#pragma unroll
      for (int d = 0; d < 4; ++d) {
        unsigned a = va + (G << 10) + (d << 12);
        TRR(tLo[G][d], a);        // kb = 8G+g   -> keys 32G+4g..+3
        TRR(tHi[G][d], a + 512);  // kb = 8G+g+4 -> keys 32G+16+4g..+3
      }
    bool actA = (ss < ssA);
    // K fragments (shared) + QK^T for both tiles
    const char* kbuf = (const char*)&Ks[buf][0];
    int swz = m16 & 7;
    f32x4 stA[8], stB[8];
    __builtin_amdgcn_s_setprio(1);
#pragma unroll
    for (int T = 0; T < 8; ++T) {
      const char* rp = kbuf + (((T << 4) + m16) << 7);
      bf16x8 kf0 = *(const bf16x8*)(rp + ((g ^ swz) << 4));
      bf16x8 kf1 = *(const bf16x8*)(rp + (((4 + g) ^ swz) << 4));
      stB[T] = MFMA16x16x32(kf0, qfB0, zero4);
      stB[T] = MFMA16x16x32(kf1, qfB1, stB[T]);
      if (actA) {
        stA[T] = MFMA16x16x32(kf0, qfA0, zero4);
        stA[T] = MFMA16x16x32(kf1, qfA1, stA[T]);
      }
    }
    __builtin_amdgcn_s_setprio(0);

    asm volatile("s_waitcnt lgkmcnt(0)" ::: "memory");
    __builtin_amdgcn_sched_barrier(0);

    // ---- chain A ----
    if (actA) {
      if (ss == ssA - 1) {  // A diagonal superstep
        int rq = qrowA - (ss << 7);
#pragma unroll
        for (int T = 0; T < 8; ++T)
#pragma unroll
          for (int r = 0; r < 4; ++r)
            if ((T << 4) + (g << 2) + r > rq) stA[T][r] = -3e38f;
      }
      float tm[8];
#pragma unroll
      for (int T = 0; T < 8; ++T)
        tm[T] = max3f(fmaxf(stA[T][0], stA[T][1]), stA[T][2], stA[T][3]);
      float u0 = max3f(tm[0], tm[1], tm[2]);
      float u1 = max3f(tm[3], tm[4], tm[5]);
      float tmax = max3f(u0, u1, fmaxf(tm[6], tm[7]));
      tmax = fmaxf(tmax, __shfl_xor(tmax, 16));
      tmax = fmaxf(tmax, __shfl_xor(tmax, 32));
      float tsc2 = tmax * C1;
      bool skip = __all(tsc2 <= m2A + THR);
      float mnew2 = skip ? m2A : fmaxf(m2A, tsc2);
      float p[8][4];
      f32x4 ts4 = zero4;
#pragma unroll
      for (int T = 0; T < 8; ++T)
#pragma unroll
        for (int r = 0; r < 4; ++r) {
          float e = __builtin_amdgcn_exp2f(fmaf(stA[T][r], C1, -mnew2));
          p[T][r] = e;
          ts4[r] += e;
        }
      if (!skip) {
        float alpha = __builtin_amdgcn_exp2f(m2A - mnew2);
        lsvA *= alpha;
#pragma unroll
        for (int d = 0; d < 4; ++d) OA[d] *= alpha;
        m2A = mnew2;
      }
      lsvA += ts4;
      bf16x8 pb[4];
#pragma unroll
      for (int G = 0; G < 4; ++G) {
        i32x4 wv;
        wv[0] = cvtpk(p[2 * G][0], p[2 * G][1]);
        wv[1] = cvtpk(p[2 * G][2], p[2 * G][3]);
        wv[2] = cvtpk(p[2 * G + 1][0], p[2 * G + 1][1]);
        wv[3] = cvtpk(p[2 * G + 1][2], p[2 * G + 1][3]);
        pb[G] = __builtin_bit_cast(bf16x8, wv);
      }
      __builtin_amdgcn_s_setprio(1);
#pragma unroll
      for (int d = 0; d < 4; ++d)
#pragma unroll
        for (int G = 0; G < 4; ++G) {
          bf16x8 vf = __builtin_shufflevector(tLo[G][d], tHi[G][d], 0, 1, 2, 3, 4, 5, 6, 7);
          OA[d] = MFMA16x16x32(vf, pb[G], OA[d]);
        }
      __builtin_amdgcn_s_setprio(0);
    }

    // ---- chain B ----
    {
      if (ss == nt - 1) {  // B diagonal superstep
        int rq = qrowB - (ss << 7);
#pragma unroll
        for (int T = 0; T < 8; ++T)
#pragma unroll
          for (int r = 0; r < 4; ++r)
            if ((T << 4) + (g << 2) + r > rq) stB[T][r] = -3e38f;
      }
      float tm[8];
#pragma unroll
      for (int T = 0; T < 8; ++T)
        tm[T] = max3f(fmaxf(stB[T][0], stB[T][1]), stB[T][2], stB[T][3]);
      float u0 = max3f(tm[0], tm[1], tm[2]);
      float u1 = max3f(tm[3], tm[4], tm[5]);
      float tmax = max3f(u0, u1, fmaxf(tm[6], tm[7]));
      tmax = fmaxf(tmax, __shfl_xor(tmax, 16));
      tmax = fmaxf(tmax, __shfl_xor(tmax, 32));
      float tsc2 = tmax * C1;
      bool skip = __all(tsc2 <= m2B + THR);
      float mnew2 = skip ? m2B : fmaxf(m2B, tsc2);
      float p[8][4];
      f32x4 ts4 = zero4;
#pragma unroll
      for (int T = 0; T < 8; ++T)
#pragma unroll
        for (int r = 0; r < 4; ++r) {
          float e = __builtin_amdgcn_exp2f(fmaf(stB[T][r], C1, -mnew2));
          p[T][r] = e;
          ts4[r] += e;
        }
      if (!skip) {
        float alpha = __builtin_amdgcn_exp2f(m2B - mnew2);
        lsvB *= alpha;
#pragma unroll
        for (int d = 0; d < 4; ++d) OB[d] *= alpha;
        m2B = mnew2;
      }
      lsvB += ts4;
      bf16x8 pb[4];
#pragma unroll
      for (int G = 0; G < 4; ++G) {
        i32x4 wv;
        wv[0] = cvtpk(p[2 * G][0], p[2 * G][1]);
        wv[1] = cvtpk(p[2 * G][2], p[2 * G][3]);
        wv[2] = cvtpk(p[2 * G + 1][0], p[2 * G + 1][1]);
        wv[3] = cvtpk(p[2 * G + 1][2], p[2 * G + 1][3]);
        pb[G] = __builtin_bit_cast(bf16x8, wv);
      }
      __builtin_amdgcn_s_setprio(1);
#pragma unroll
      for (int d = 0; d < 4; ++d)
#pragma unroll
        for (int G = 0; G < 4; ++G) {
          bf16x8 vf = __builtin_shufflevector(tLo[G][d], tHi[G][d], 0, 1, 2, 3, 4, 5, 6, 7);
          OB[d] = MFMA16x16x32(vf, pb[G], OB[d]);
        }
      __builtin_amdgcn_s_setprio(0);
    }

    __syncthreads();
    buf ^= 1;
  }

  // epilogue: reduce deferred lsum, scale, store (both tiles)
  {
    float s = (lsvA[0] + lsvA[1]) + (lsvA[2] + lsvA[3]);
    s += __shfl_xor(s, 16);
    s += __shfl_xor(s, 32);
    float inv = 1.0f / s;
    unsigned short* op = out + (long)(b * 2048 + qrowA) * 1024 + h * 64;
#pragma unroll
    for (int d = 0; d < 4; ++d) {
      i32x2 pk;
      pk[0] = (int)cvtpk(OA[d][0] * inv, OA[d][1] * inv);
      pk[1] = (int)cvtpk(OA[d][2] * inv, OA[d][3] * inv);
      *reinterpret_cast<i32x2*>(op + (d << 4) + (g << 2)) = pk;
    }
  }
  {
    float s = (lsvB[0] + lsvB[1]) + (lsvB[2] + lsvB[3]);
    s += __shfl_xor(s, 16);
    s += __shfl_xor(s, 32);
    float inv = 1.0f / s;
    unsigned short* op = out + (long)(b * 2048 + qrowB) * 1024 + h * 64;
#pragma unroll
    for (int d = 0; d < 4; ++d) {
      i32x2 pk;
      pk[0] = (int)cvtpk(OB[d][0] * inv, OB[d][1] * inv);
      pk[1] = (int)cvtpk(OB[d][2] * inv, OB[d][3] * inv);
      *reinterpret_cast<i32x2*>(op + (d << 4) + (g << 2)) = pk;
    }
  }
}

extern "C" void kernel_launch(void* const* d_in, const int* in_sizes, int n_in,
                              void* d_out, int out_size, void* d_ws, size_t ws_size,
                              hipStream_t stream) {
  const float* x     = (const float*)d_in[0];
  const float* W_qkv = (const float*)d_in[1];
  const float* b_qkv = (const float*)d_in[2];
  const float* W_out = (const float*)d_in[3];
  const float* b_out = (const float*)d_in[4];

  char* ws = (char*)d_ws;
  unsigned short* xb    = (unsigned short*)ws;                  // 8 MB (x bf16; reused as attn out)
  unsigned short* wqkvT = (unsigned short*)(ws + (8l << 20));   // 6 MB
  unsigned short* woutT = (unsigned short*)(ws + (14l << 20));  // 2 MB
  unsigned short* qkv   = (unsigned short*)(ws + (16l << 20));  // 24 MB

  conv_bf16<<<2048, 256, 0, stream>>>(x, xb, 524288);
  trans_f32_bf16<<<dim3(96, 32), dim3(32, 8), 0, stream>>>(W_qkv, wqkvT, 1024, 3072);
  trans_f32_bf16<<<dim3(32, 32), dim3(32, 8), 0, stream>>>(W_out, woutT, 1024, 1024);
  gemm_bt<1><<<dim3(24, 32), 256, 0, stream>>>(xb, wqkvT, b_qkv, (void*)qkv, 4096, 3072, 1024);
  attn_fwd<<<dim3(32, 16), 256, 0, stream>>>(qkv, xb);
  gemm_bt<0><<<dim3(8, 32), 256, 0, stream>>>(xb, woutT, b_out, d_out, 4096, 1024, 1024);
}